// Round 8
// baseline (488.965 us; speedup 1.0000x reference)
//
#include <hip/hip_runtime.h>

// GCN link predictor, fp32 — round 8:
//  * deg_kernel: per-XCD replicated histograms (s_getreg XCC_ID) + workgroup-scope
//    atomics -> RMW stays in local TCC instead of HBM round trip per atomic
//    (round 7 counters: WRITE_SIZE 62MB for 800KB output = 32B HBM write per atomic)
//  * mlp gather: 2 rounds x 16 outstanding loads (was 4 x 8) — latency-bound phase
//
// ws layout (float units):
//   0        norm_src [N]
//   100000   norm_dst [N]
//   200000   cursor (int) [N]
//   300000   deg_in (int) [N]
//   400000   row_ptr (int) [N+1]
//   500004   cedge (float4) [E]          (src, w_l0, w_l1, w_l2) per edge
//   4500004  hw   [N*64]   (pre-layer0: deg replicas 16*N ints + scan scratch)
//   10900004 agg  [N*64]
// total 17300004 floats = 69.2 MB

#define NN 100000
#define NE 1000000
#define NP 100000
#define SCAN_NB 98

__device__ __forceinline__ void row_fma(float4& acc, float xv, const float4& wv) {
    acc.x = fmaf(xv, wv.x, acc.x);
    acc.y = fmaf(xv, wv.y, acc.y);
    acc.z = fmaf(xv, wv.z, acc.z);
    acc.w = fmaf(xv, wv.w, acc.w);
}

// per-XCD replicated degree count: each XCD's atomics stay in its own L2 (workgroup scope).
__global__ void deg_kernel(const int4* __restrict__ src4, const int4* __restrict__ dst4,
                           int* __restrict__ repl, int E4) {
    int xcc;
    asm volatile("s_getreg_b32 %0, hwreg(HW_REG_XCC_ID)" : "=s"(xcc));
    xcc &= 7;
    int* dout = repl + xcc * NN;
    int* din  = repl + (8 + xcc) * NN;
    int tid = blockIdx.x * blockDim.x + threadIdx.x;
    if (tid < E4) {
        int4 s = src4[tid], d = dst4[tid];
        __hip_atomic_fetch_add(&dout[s.x], 1, __ATOMIC_RELAXED, __HIP_MEMORY_SCOPE_WORKGROUP);
        __hip_atomic_fetch_add(&dout[s.y], 1, __ATOMIC_RELAXED, __HIP_MEMORY_SCOPE_WORKGROUP);
        __hip_atomic_fetch_add(&dout[s.z], 1, __ATOMIC_RELAXED, __HIP_MEMORY_SCOPE_WORKGROUP);
        __hip_atomic_fetch_add(&dout[s.w], 1, __ATOMIC_RELAXED, __HIP_MEMORY_SCOPE_WORKGROUP);
        __hip_atomic_fetch_add(&din[d.x], 1, __ATOMIC_RELAXED, __HIP_MEMORY_SCOPE_WORKGROUP);
        __hip_atomic_fetch_add(&din[d.y], 1, __ATOMIC_RELAXED, __HIP_MEMORY_SCOPE_WORKGROUP);
        __hip_atomic_fetch_add(&din[d.z], 1, __ATOMIC_RELAXED, __HIP_MEMORY_SCOPE_WORKGROUP);
        __hip_atomic_fetch_add(&din[d.w], 1, __ATOMIC_RELAXED, __HIP_MEMORY_SCOPE_WORKGROUP);
    }
}

// sum the 8 replicas, produce norms + deg_in (for the scan).
__global__ void reduce_norm_kernel(const int* __restrict__ repl, float* __restrict__ norm_src,
                                   float* __restrict__ norm_dst, int* __restrict__ deg_in, int n) {
    int i = blockIdx.x * blockDim.x + threadIdx.x;
    if (i < n) {
        int so = 0, si = 0;
#pragma unroll
        for (int x = 0; x < 8; ++x) {
            so += repl[x * NN + i];
            si += repl[(8 + x) * NN + i];
        }
        norm_src[i] = rsqrtf(fmaxf((float)so, 1.0f));
        norm_dst[i] = rsqrtf(fmaxf((float)si, 1.0f));
        deg_in[i] = si;
    }
}

__global__ __launch_bounds__(1024) void scan_block(const int* __restrict__ deg,
                                                   int* __restrict__ tmp_excl,
                                                   int* __restrict__ blocksums, int n) {
    __shared__ int wsums[16];
    const int i = blockIdx.x * 1024 + threadIdx.x;
    const int lane = threadIdx.x & 63, w = threadIdx.x >> 6;
    int v = (i < n) ? deg[i] : 0;
    int s = v;
#pragma unroll
    for (int off = 1; off < 64; off <<= 1) {
        int u = __shfl_up(s, off, 64);
        if (lane >= off) s += u;
    }
    if (lane == 63) wsums[w] = s;
    __syncthreads();
    if (w == 0) {
        int wv = (lane < 16) ? wsums[lane] : 0;
#pragma unroll
        for (int off = 1; off < 16; off <<= 1) {
            int u = __shfl_up(wv, off, 64);
            if (lane >= off) wv += u;
        }
        if (lane < 16) wsums[lane] = wv;
    }
    __syncthreads();
    int excl = s - v + (w > 0 ? wsums[w - 1] : 0);
    if (i < n) tmp_excl[i] = excl;
    if (threadIdx.x == 1023) blocksums[blockIdx.x] = excl + v;
}

__global__ void scan_sums(int* __restrict__ bs, int nb) {
    __shared__ int wtot[2];
    const int t = threadIdx.x;  // 128 threads
    const int lane = t & 63, w = t >> 6;
    int v = (t < nb) ? bs[t] : 0;
    int s = v;
#pragma unroll
    for (int off = 1; off < 64; off <<= 1) {
        int u = __shfl_up(s, off, 64);
        if (lane >= off) s += u;
    }
    if (lane == 63) wtot[w] = s;
    __syncthreads();
    int excl = s - v + (w == 1 ? wtot[0] : 0);
    if (t < nb) bs[t] = excl;
}

__global__ __launch_bounds__(1024) void scan_apply(const int* __restrict__ tmp_excl,
                                                   const int* __restrict__ bs,
                                                   int* __restrict__ row_ptr,
                                                   int* __restrict__ cursor, int n) {
    const int i = blockIdx.x * 1024 + threadIdx.x;
    if (i < n) {
        int r = tmp_excl[i] + bs[blockIdx.x];
        row_ptr[i] = r;
        cursor[i] = r;
    }
    if (i == 0) row_ptr[n] = NE;
}

// pack each edge into its dst row: one scattered 16B write per edge.
__global__ void csr_fill(const int* __restrict__ src, const int* __restrict__ dst,
                         const float* __restrict__ ew, int* __restrict__ cursor,
                         float4* __restrict__ cedge, int E) {
    int tid = blockIdx.x * blockDim.x + threadIdx.x;
    int stride = gridDim.x * blockDim.x;
    for (int e = tid; e < E; e += stride) {
        int d = dst[e];
        int slot = atomicAdd(&cursor[d], 1);
        float4 c;
        c.x = __int_as_float(src[e]);
        c.y = ew[e];
        c.z = ew[NE + e];
        c.w = ew[2 * NE + e];
        cedge[slot] = c;
    }
}

// CSR pull aggregation, one wave per dst node, 8-wide batched loads. Fused epilogue:
//  FINAL=0: out = relu(a*norm_dst + bias)*norm_src   (input for next pure GEMM)
//  FINAL=1: out = a*norm_dst + bias                  (b2; final conv output, no relu)
template <int WSEL, bool FINAL>
__global__ __launch_bounds__(256) void aggregate(const float* __restrict__ hw,
                                                 const float4* __restrict__ cedge,
                                                 const int* __restrict__ row_ptr,
                                                 const float* __restrict__ norm_src,
                                                 const float* __restrict__ norm_dst,
                                                 const float* __restrict__ bias,
                                                 float* __restrict__ outx, int n) {
    const int lane = threadIdx.x & 63;
    const int gw = (blockIdx.x * blockDim.x + threadIdx.x) >> 6;
    const int nw = (gridDim.x * blockDim.x) >> 6;
    const float blane = bias[lane];
    for (int node = gw; node < n; node += nw) {
        int beg = row_ptr[node], end = row_ptr[node + 1];
        float a0 = 0.f, a1 = 0.f, a2 = 0.f, a3 = 0.f;
        int i = beg;
        for (; i + 7 < end; i += 8) {
            float4 c0 = cedge[i + 0], c1 = cedge[i + 1], c2 = cedge[i + 2], c3 = cedge[i + 3];
            float4 c4 = cedge[i + 4], c5 = cedge[i + 5], c6 = cedge[i + 6], c7 = cedge[i + 7];
            float h0 = hw[__float_as_int(c0.x) * 64 + lane];
            float h1 = hw[__float_as_int(c1.x) * 64 + lane];
            float h2 = hw[__float_as_int(c2.x) * 64 + lane];
            float h3 = hw[__float_as_int(c3.x) * 64 + lane];
            float h4 = hw[__float_as_int(c4.x) * 64 + lane];
            float h5 = hw[__float_as_int(c5.x) * 64 + lane];
            float h6 = hw[__float_as_int(c6.x) * 64 + lane];
            float h7 = hw[__float_as_int(c7.x) * 64 + lane];
            a0 = fmaf(h0, (WSEL == 0) ? c0.y : (WSEL == 1) ? c0.z : c0.w, a0);
            a1 = fmaf(h1, (WSEL == 0) ? c1.y : (WSEL == 1) ? c1.z : c1.w, a1);
            a2 = fmaf(h2, (WSEL == 0) ? c2.y : (WSEL == 1) ? c2.z : c2.w, a2);
            a3 = fmaf(h3, (WSEL == 0) ? c3.y : (WSEL == 1) ? c3.z : c3.w, a3);
            a0 = fmaf(h4, (WSEL == 0) ? c4.y : (WSEL == 1) ? c4.z : c4.w, a0);
            a1 = fmaf(h5, (WSEL == 0) ? c5.y : (WSEL == 1) ? c5.z : c5.w, a1);
            a2 = fmaf(h6, (WSEL == 0) ? c6.y : (WSEL == 1) ? c6.z : c6.w, a2);
            a3 = fmaf(h7, (WSEL == 0) ? c7.y : (WSEL == 1) ? c7.z : c7.w, a3);
        }
        for (; i + 1 < end; i += 2) {
            float4 c0 = cedge[i], c1 = cedge[i + 1];
            float h0 = hw[__float_as_int(c0.x) * 64 + lane];
            float h1 = hw[__float_as_int(c1.x) * 64 + lane];
            a0 = fmaf(h0, (WSEL == 0) ? c0.y : (WSEL == 1) ? c0.z : c0.w, a0);
            a1 = fmaf(h1, (WSEL == 0) ? c1.y : (WSEL == 1) ? c1.z : c1.w, a1);
        }
        if (i < end) {
            float4 c0 = cedge[i];
            float h0 = hw[__float_as_int(c0.x) * 64 + lane];
            a0 = fmaf(h0, (WSEL == 0) ? c0.y : (WSEL == 1) ? c0.z : c0.w, a0);
        }
        float a = (a0 + a1) + (a2 + a3);
        float nd = norm_dst[node];
        float t;
        if (FINAL) {
            t = fmaf(a, nd, blane);
        } else {
            t = fmaxf(fmaf(a, nd, blane), 0.f) * norm_src[node];
        }
        outx[node * 64 + lane] = t;
    }
}

// 64-row GEMM tile, W in LDS (staged once), X direct from global (wave-broadcast).
// No per-tile barriers. out[row][j] = (SCALE ? norm_src[row] : 1) * sum_k in[row][k]*W[k][j]
template <int K, bool SCALE>
__global__ __launch_bounds__(256, 5) void gemm_tile(const float* __restrict__ in,
                                                    const float* __restrict__ W,
                                                    const float* __restrict__ norm_src,
                                                    float* __restrict__ out, int n) {
    __shared__ float Ws[K * 64];
    const int tid = threadIdx.x;
    for (int i = tid; i < K * 16; i += 256) ((float4*)Ws)[i] = ((const float4*)W)[i];
    __syncthreads();  // the only barrier in the kernel

    const int tr = tid >> 4, tc = tid & 15;
    const int row0 = blockIdx.x * 64 + tr * 4;
    const float* xr0 = in + (size_t)min(row0 + 0, n - 1) * K;
    const float* xr1 = in + (size_t)min(row0 + 1, n - 1) * K;
    const float* xr2 = in + (size_t)min(row0 + 2, n - 1) * K;
    const float* xr3 = in + (size_t)min(row0 + 3, n - 1) * K;

    float4 acc0 = {0, 0, 0, 0}, acc1 = {0, 0, 0, 0}, acc2 = {0, 0, 0, 0}, acc3 = {0, 0, 0, 0};
#pragma unroll 4
    for (int k4 = 0; k4 < K / 4; ++k4) {
        const int kb = k4 * 4;
        float4 xv0 = *(const float4*)&xr0[kb];
        float4 xv1 = *(const float4*)&xr1[kb];
        float4 xv2 = *(const float4*)&xr2[kb];
        float4 xv3 = *(const float4*)&xr3[kb];
        const float* wb = &Ws[kb * 64 + tc * 4];
        float4 wk;
        wk = *(const float4*)(wb);
        row_fma(acc0, xv0.x, wk); row_fma(acc1, xv1.x, wk); row_fma(acc2, xv2.x, wk); row_fma(acc3, xv3.x, wk);
        wk = *(const float4*)(wb + 64);
        row_fma(acc0, xv0.y, wk); row_fma(acc1, xv1.y, wk); row_fma(acc2, xv2.y, wk); row_fma(acc3, xv3.y, wk);
        wk = *(const float4*)(wb + 128);
        row_fma(acc0, xv0.z, wk); row_fma(acc1, xv1.z, wk); row_fma(acc2, xv2.z, wk); row_fma(acc3, xv3.z, wk);
        wk = *(const float4*)(wb + 192);
        row_fma(acc0, xv0.w, wk); row_fma(acc1, xv1.w, wk); row_fma(acc2, xv2.w, wk); row_fma(acc3, xv3.w, wk);
    }

#pragma unroll
    for (int i = 0; i < 4; ++i) {
        int row = row0 + i;
        if (row < n) {
            float4 o = (i == 0) ? acc0 : (i == 1) ? acc1 : (i == 2) ? acc2 : acc3;
            if (SCALE) {
                float ns = norm_src[row];
                o.x *= ns; o.y *= ns; o.z *= ns; o.w *= ns;
            }
            *(float4*)&out[row * 64 + tc * 4] = o;
        }
    }
}

#define ZST 76  // Zs row stride (x4B = 304B, 16B-aligned)

// 64 pairs per block (grid = 3125): Z staged in LDS, P0/P1 from global (L1-broadcast).
__global__ __launch_bounds__(256) void mlp_tile(const float* __restrict__ hfin,
                                                const float* __restrict__ P0,
                                                const float* __restrict__ pb0,
                                                const float* __restrict__ P1,
                                                const float* __restrict__ pb1,
                                                const float* __restrict__ P2,
                                                const float* __restrict__ pb2,
                                                const int* __restrict__ pos_src,
                                                const int* __restrict__ pos_dst,
                                                const int* __restrict__ neg_src,
                                                const int* __restrict__ neg_dst,
                                                float* __restrict__ out, int P) {
    __shared__ float Zs[64][ZST];
    __shared__ float pb0s[64], pb1s[64], P2s[64];
    __shared__ int pas[64], pbs[64];
    const int tid = threadIdx.x;
    const int base = blockIdx.x << 6;
    if (tid < 64) {
        pb0s[tid] = pb0[tid];
        pb1s[tid] = pb1[tid];
        P2s[tid] = P2[tid];
        int p = base + tid;
        pas[tid] = (p < P) ? pos_src[p] : neg_src[p - P];
        pbs[tid] = (p < P) ? pos_dst[p] : neg_dst[p - P];
    }
    const float pb2v = pb2[0];
    const int lane = tid & 63, w = tid >> 6;
    const int tr = tid >> 4, tc = tid & 15;
    __syncthreads();

    // gather + product: wave w owns pairs [w*16, w*16+16); 2 rounds x 16 loads in flight
    {
        const int pbase = w * 16;
#pragma unroll
        for (int r = 0; r < 2; ++r) {
            const int p0 = pbase + r * 8;
            int a0 = pas[p0 + 0], b0 = pbs[p0 + 0];
            int a1 = pas[p0 + 1], b1 = pbs[p0 + 1];
            int a2 = pas[p0 + 2], b2 = pbs[p0 + 2];
            int a3 = pas[p0 + 3], b3 = pbs[p0 + 3];
            int a4 = pas[p0 + 4], b4 = pbs[p0 + 4];
            int a5 = pas[p0 + 5], b5 = pbs[p0 + 5];
            int a6 = pas[p0 + 6], b6 = pbs[p0 + 6];
            int a7 = pas[p0 + 7], b7 = pbs[p0 + 7];
            float ha0 = hfin[a0 * 64 + lane], hb0 = hfin[b0 * 64 + lane];
            float ha1 = hfin[a1 * 64 + lane], hb1 = hfin[b1 * 64 + lane];
            float ha2 = hfin[a2 * 64 + lane], hb2 = hfin[b2 * 64 + lane];
            float ha3 = hfin[a3 * 64 + lane], hb3 = hfin[b3 * 64 + lane];
            float ha4 = hfin[a4 * 64 + lane], hb4 = hfin[b4 * 64 + lane];
            float ha5 = hfin[a5 * 64 + lane], hb5 = hfin[b5 * 64 + lane];
            float ha6 = hfin[a6 * 64 + lane], hb6 = hfin[b6 * 64 + lane];
            float ha7 = hfin[a7 * 64 + lane], hb7 = hfin[b7 * 64 + lane];
            Zs[p0 + 0][lane] = ha0 * hb0;
            Zs[p0 + 1][lane] = ha1 * hb1;
            Zs[p0 + 2][lane] = ha2 * hb2;
            Zs[p0 + 3][lane] = ha3 * hb3;
            Zs[p0 + 4][lane] = ha4 * hb4;
            Zs[p0 + 5][lane] = ha5 * hb5;
            Zs[p0 + 6][lane] = ha6 * hb6;
            Zs[p0 + 7][lane] = ha7 * hb7;
        }
    }
    __syncthreads();

    // layer 0: Z1 = relu(Z @ P0 + pb0)
    float4 acc0, acc1, acc2, acc3;
    {
        float4 binit = *(const float4*)&pb0s[tc * 4];
        acc0 = binit; acc1 = binit; acc2 = binit; acc3 = binit;
    }
#pragma unroll 4
    for (int k4 = 0; k4 < 16; ++k4) {
        const int kb = k4 * 4;
        float4 xv0 = *(const float4*)&Zs[tr * 4 + 0][kb];
        float4 xv1 = *(const float4*)&Zs[tr * 4 + 1][kb];
        float4 xv2 = *(const float4*)&Zs[tr * 4 + 2][kb];
        float4 xv3 = *(const float4*)&Zs[tr * 4 + 3][kb];
        const float* wb = &P0[kb * 64 + tc * 4];
        float4 wk;
        wk = *(const float4*)(wb);
        row_fma(acc0, xv0.x, wk); row_fma(acc1, xv1.x, wk); row_fma(acc2, xv2.x, wk); row_fma(acc3, xv3.x, wk);
        wk = *(const float4*)(wb + 64);
        row_fma(acc0, xv0.y, wk); row_fma(acc1, xv1.y, wk); row_fma(acc2, xv2.y, wk); row_fma(acc3, xv3.y, wk);
        wk = *(const float4*)(wb + 128);
        row_fma(acc0, xv0.z, wk); row_fma(acc1, xv1.z, wk); row_fma(acc2, xv2.z, wk); row_fma(acc3, xv3.z, wk);
        wk = *(const float4*)(wb + 192);
        row_fma(acc0, xv0.w, wk); row_fma(acc1, xv1.w, wk); row_fma(acc2, xv2.w, wk); row_fma(acc3, xv3.w, wk);
    }
    __syncthreads();
#pragma unroll
    for (int i = 0; i < 4; ++i) {
        float4 o = (i == 0) ? acc0 : (i == 1) ? acc1 : (i == 2) ? acc2 : acc3;
        o.x = fmaxf(o.x, 0.f); o.y = fmaxf(o.y, 0.f); o.z = fmaxf(o.z, 0.f); o.w = fmaxf(o.w, 0.f);
        *(float4*)&Zs[tr * 4 + i][tc * 4] = o;
    }
    __syncthreads();

    // layer 1: Z2 = relu(Z1 @ P1 + pb1)
    {
        float4 binit = *(const float4*)&pb1s[tc * 4];
        acc0 = binit; acc1 = binit; acc2 = binit; acc3 = binit;
    }
#pragma unroll 4
    for (int k4 = 0; k4 < 16; ++k4) {
        const int kb = k4 * 4;
        float4 xv0 = *(const float4*)&Zs[tr * 4 + 0][kb];
        float4 xv1 = *(const float4*)&Zs[tr * 4 + 1][kb];
        float4 xv2 = *(const float4*)&Zs[tr * 4 + 2][kb];
        float4 xv3 = *(const float4*)&Zs[tr * 4 + 3][kb];
        const float* wb = &P1[kb * 64 + tc * 4];
        float4 wk;
        wk = *(const float4*)(wb);
        row_fma(acc0, xv0.x, wk); row_fma(acc1, xv1.x, wk); row_fma(acc2, xv2.x, wk); row_fma(acc3, xv3.x, wk);
        wk = *(const float4*)(wb + 64);
        row_fma(acc0, xv0.y, wk); row_fma(acc1, xv1.y, wk); row_fma(acc2, xv2.y, wk); row_fma(acc3, xv3.y, wk);
        wk = *(const float4*)(wb + 128);
        row_fma(acc0, xv0.z, wk); row_fma(acc1, xv1.z, wk); row_fma(acc2, xv2.z, wk); row_fma(acc3, xv3.z, wk);
        wk = *(const float4*)(wb + 192);
        row_fma(acc0, xv0.w, wk); row_fma(acc1, xv1.w, wk); row_fma(acc2, xv2.w, wk); row_fma(acc3, xv3.w, wk);
    }
    __syncthreads();
#pragma unroll
    for (int i = 0; i < 4; ++i) {
        float4 o = (i == 0) ? acc0 : (i == 1) ? acc1 : (i == 2) ? acc2 : acc3;
        o.x = fmaxf(o.x, 0.f); o.y = fmaxf(o.y, 0.f); o.z = fmaxf(o.z, 0.f); o.w = fmaxf(o.w, 0.f);
        *(float4*)&Zs[tr * 4 + i][tc * 4] = o;
    }
    __syncthreads();

    // final GEMV: out[p] = Z2[p] . P2 + pb2
    {
        int p = tid >> 2, kq = tid & 3;
        float s = 0.f;
#pragma unroll
        for (int i = 0; i < 16; ++i) s = fmaf(Zs[p][kq * 16 + i], P2s[kq * 16 + i], s);
        s += __shfl_xor(s, 1, 64);
        s += __shfl_xor(s, 2, 64);
        if (kq == 0) out[base + p] = s + pb2v;
    }
}

extern "C" void kernel_launch(void* const* d_in, const int* in_sizes, int n_in,
                              void* d_out, int out_size, void* d_ws, size_t ws_size,
                              hipStream_t stream) {
    const float* x     = (const float*)d_in[0];
    const float* ew    = (const float*)d_in[1];  // (3, E)
    const int* src     = (const int*)d_in[2];
    const int* dst     = (const int*)d_in[3];
    const int* pos_src = (const int*)d_in[4];
    const int* pos_dst = (const int*)d_in[5];
    const int* neg_src = (const int*)d_in[6];
    const int* neg_dst = (const int*)d_in[7];
    const float* W0    = (const float*)d_in[8];
    const float* b0    = (const float*)d_in[9];
    const float* W1    = (const float*)d_in[10];
    const float* b1    = (const float*)d_in[11];
    const float* W2    = (const float*)d_in[12];
    const float* b2    = (const float*)d_in[13];
    const float* P0    = (const float*)d_in[14];
    const float* pb0   = (const float*)d_in[15];
    const float* P1    = (const float*)d_in[16];
    const float* pb1   = (const float*)d_in[17];
    const float* P2    = (const float*)d_in[18];
    const float* pb2   = (const float*)d_in[19];
    float* out = (float*)d_out;

    float* ws = (float*)d_ws;
    float* norm_src = ws;                     // N
    float* norm_dst = ws + 100000;            // N
    int* cursor     = (int*)(ws + 200000);    // N
    int* deg_in     = (int*)(ws + 300000);    // N
    int* row_ptr    = (int*)(ws + 400000);    // N+1
    float4* cedge   = (float4*)(ws + 500004); // E
    float* hw       = ws + 4500004;           // N*64
    float* agg      = ws + 10900004;          // N*64

    // pre-layer0 scratch inside hw region (not yet live)
    int* repl      = (int*)hw;            // 16*NN ints: [deg_out x8][deg_in x8]
    int* tmp_excl  = (int*)hw + 16 * NN;  // NN
    int* blocksums = (int*)hw + 17 * NN;  // SCAN_NB

    hipMemsetAsync(repl, 0, 16 * NN * sizeof(int), stream);
    deg_kernel<<<(NE / 4 + 255) / 256, 256, 0, stream>>>((const int4*)src, (const int4*)dst,
                                                         repl, NE / 4);
    reduce_norm_kernel<<<(NN + 255) / 256, 256, 0, stream>>>(repl, norm_src, norm_dst, deg_in, NN);
    scan_block<<<SCAN_NB, 1024, 0, stream>>>(deg_in, tmp_excl, blocksums, NN);
    scan_sums<<<1, 128, 0, stream>>>(blocksums, SCAN_NB);
    scan_apply<<<SCAN_NB, 1024, 0, stream>>>(tmp_excl, blocksums, row_ptr, cursor, NN);
    csr_fill<<<2048, 256, 0, stream>>>(src, dst, ew, cursor, cedge, NE);

    const int NT = (NN + 63) / 64;  // 1563 tiles

    // layer 0: hw = (x @ W0) * ns   (agg epilogue produces relu(a*nd+b0)*ns)
    gemm_tile<128, true><<<NT, 256, 0, stream>>>(x, W0, norm_src, hw, NN);
    aggregate<0, false><<<4096, 256, 0, stream>>>(hw, cedge, row_ptr, norm_src, norm_dst, b0, agg, NN);
    // layer 1
    gemm_tile<64, false><<<NT, 256, 0, stream>>>(agg, W1, nullptr, hw, NN);
    aggregate<1, false><<<4096, 256, 0, stream>>>(hw, cedge, row_ptr, norm_src, norm_dst, b1, agg, NN);
    // layer 2 (final: agg <- a*nd + b2, no relu — this IS hfin)
    gemm_tile<64, false><<<NT, 256, 0, stream>>>(agg, W2, nullptr, hw, NN);
    aggregate<2, true><<<4096, 256, 0, stream>>>(hw, cedge, row_ptr, norm_src, norm_dst, b2, agg, NN);

    // MLP over pos & neg pairs (grid = exactly one 64-pair tile per block)
    mlp_tile<<<(2 * NP) / 64, 256, 0, stream>>>(agg, P0, pb0, P1, pb1, P2, pb2,
                                                pos_src, pos_dst, neg_src, neg_dst, out, NP);
}

// Round 9
// 480.035 us; speedup vs baseline: 1.0186x; 1.0186x over previous
//
#include <hip/hip_runtime.h>

// GCN link predictor, fp32 — round 9: algebraic fusion.
// GraphConv is bilinear: sum_e w_e ((h ns)[src] @ W) = (sum_e (w_e ns[src]) h[src]) @ W.
// -> fold ns into cedge weights (csr_fill), aggregate RAW h, apply W per dst node
//    inside the aggregate kernel (W in LDS, 4-node batched GEMV).
// Kills all 3 standalone gemm dispatches + the hw round trip per layer.
//
// ws layout (float units):
//   0        norm_src [N]
//   100000   norm_dst [N]
//   200000   cursor (int) [N]
//   300000   deg_in (int) [N]
//   400000   row_ptr (int) [N+1]
//   500004   cedge (float4) [E]        (src, ns*w_l0, ns*w_l1, ns*w_l2)
//   4500004  tA   [N*64]  (pre-layer0: deg replicas 16N ints + scan scratch)
//   10900004 tB   [N*64]
// total 17300004 floats = 69.2 MB

#define NN 100000
#define NE 1000000
#define NP 100000
#define SCAN_NB 98

__device__ __forceinline__ void row_fma(float4& acc, float xv, const float4& wv) {
    acc.x = fmaf(xv, wv.x, acc.x);
    acc.y = fmaf(xv, wv.y, acc.y);
    acc.z = fmaf(xv, wv.z, acc.z);
    acc.w = fmaf(xv, wv.w, acc.w);
}

// per-XCD replicated degree count: atomics stay in the local (XCD) L2.
__global__ void deg_kernel(const int4* __restrict__ src4, const int4* __restrict__ dst4,
                           int* __restrict__ repl, int E4) {
    int xcc;
    asm volatile("s_getreg_b32 %0, hwreg(HW_REG_XCC_ID)" : "=s"(xcc));
    xcc &= 7;
    int* dout = repl + xcc * NN;
    int* din  = repl + (8 + xcc) * NN;
    int tid = blockIdx.x * blockDim.x + threadIdx.x;
    if (tid < E4) {
        int4 s = src4[tid], d = dst4[tid];
        __hip_atomic_fetch_add(&dout[s.x], 1, __ATOMIC_RELAXED, __HIP_MEMORY_SCOPE_WORKGROUP);
        __hip_atomic_fetch_add(&dout[s.y], 1, __ATOMIC_RELAXED, __HIP_MEMORY_SCOPE_WORKGROUP);
        __hip_atomic_fetch_add(&dout[s.z], 1, __ATOMIC_RELAXED, __HIP_MEMORY_SCOPE_WORKGROUP);
        __hip_atomic_fetch_add(&dout[s.w], 1, __ATOMIC_RELAXED, __HIP_MEMORY_SCOPE_WORKGROUP);
        __hip_atomic_fetch_add(&din[d.x], 1, __ATOMIC_RELAXED, __HIP_MEMORY_SCOPE_WORKGROUP);
        __hip_atomic_fetch_add(&din[d.y], 1, __ATOMIC_RELAXED, __HIP_MEMORY_SCOPE_WORKGROUP);
        __hip_atomic_fetch_add(&din[d.z], 1, __ATOMIC_RELAXED, __HIP_MEMORY_SCOPE_WORKGROUP);
        __hip_atomic_fetch_add(&din[d.w], 1, __ATOMIC_RELAXED, __HIP_MEMORY_SCOPE_WORKGROUP);
    }
}

__global__ void reduce_norm_kernel(const int* __restrict__ repl, float* __restrict__ norm_src,
                                   float* __restrict__ norm_dst, int* __restrict__ deg_in, int n) {
    int i = blockIdx.x * blockDim.x + threadIdx.x;
    if (i < n) {
        int so = 0, si = 0;
#pragma unroll
        for (int x = 0; x < 8; ++x) {
            so += repl[x * NN + i];
            si += repl[(8 + x) * NN + i];
        }
        norm_src[i] = rsqrtf(fmaxf((float)so, 1.0f));
        norm_dst[i] = rsqrtf(fmaxf((float)si, 1.0f));
        deg_in[i] = si;
    }
}

__global__ __launch_bounds__(1024) void scan_block(const int* __restrict__ deg,
                                                   int* __restrict__ tmp_excl,
                                                   int* __restrict__ blocksums, int n) {
    __shared__ int wsums[16];
    const int i = blockIdx.x * 1024 + threadIdx.x;
    const int lane = threadIdx.x & 63, w = threadIdx.x >> 6;
    int v = (i < n) ? deg[i] : 0;
    int s = v;
#pragma unroll
    for (int off = 1; off < 64; off <<= 1) {
        int u = __shfl_up(s, off, 64);
        if (lane >= off) s += u;
    }
    if (lane == 63) wsums[w] = s;
    __syncthreads();
    if (w == 0) {
        int wv = (lane < 16) ? wsums[lane] : 0;
#pragma unroll
        for (int off = 1; off < 16; off <<= 1) {
            int u = __shfl_up(wv, off, 64);
            if (lane >= off) wv += u;
        }
        if (lane < 16) wsums[lane] = wv;
    }
    __syncthreads();
    int excl = s - v + (w > 0 ? wsums[w - 1] : 0);
    if (i < n) tmp_excl[i] = excl;
    if (threadIdx.x == 1023) blocksums[blockIdx.x] = excl + v;
}

__global__ void scan_sums(int* __restrict__ bs, int nb) {
    __shared__ int wtot[2];
    const int t = threadIdx.x;  // 128 threads
    const int lane = t & 63, w = t >> 6;
    int v = (t < nb) ? bs[t] : 0;
    int s = v;
#pragma unroll
    for (int off = 1; off < 64; off <<= 1) {
        int u = __shfl_up(s, off, 64);
        if (lane >= off) s += u;
    }
    if (lane == 63) wtot[w] = s;
    __syncthreads();
    int excl = s - v + (w == 1 ? wtot[0] : 0);
    if (t < nb) bs[t] = excl;
}

__global__ __launch_bounds__(1024) void scan_apply(const int* __restrict__ tmp_excl,
                                                   const int* __restrict__ bs,
                                                   int* __restrict__ row_ptr,
                                                   int* __restrict__ cursor, int n) {
    const int i = blockIdx.x * 1024 + threadIdx.x;
    if (i < n) {
        int r = tmp_excl[i] + bs[blockIdx.x];
        row_ptr[i] = r;
        cursor[i] = r;
    }
    if (i == 0) row_ptr[n] = NE;
}

// pack each edge into its dst row; fold norm_src[src] into all 3 layer weights.
__global__ void csr_fill(const int* __restrict__ src, const int* __restrict__ dst,
                         const float* __restrict__ ew, const float* __restrict__ norm_src,
                         int* __restrict__ cursor, float4* __restrict__ cedge, int E) {
    int tid = blockIdx.x * blockDim.x + threadIdx.x;
    int stride = gridDim.x * blockDim.x;
    for (int e = tid; e < E; e += stride) {
        int s = src[e];
        int d = dst[e];
        float nsv = norm_src[s];
        int slot = atomicAdd(&cursor[d], 1);
        float4 c;
        c.x = __int_as_float(s);
        c.y = ew[e] * nsv;
        c.z = ew[NE + e] * nsv;
        c.w = ew[2 * NE + e] * nsv;
        cedge[slot] = c;
    }
}

// Fused GraphConv layer: per dst node, A = sum_e cw_e * t_in[src_e] (raw features),
// then out = epilogue(A @ W). One wave per node, 4 nodes batched per GEMV
// (one Ws row feeds 4 FMAs -> 4x W-operand reuse). W in LDS (staged once).
//  FINAL=0: out = relu((A@W)*nd + b)      FINAL=1: out = (A@W)*nd + b   (b2)
template <int K, int WSEL, bool FINAL>
__global__ __launch_bounds__(256) void fused_layer(const float* __restrict__ tin,
                                                   const float4* __restrict__ cedge,
                                                   const int* __restrict__ row_ptr,
                                                   const float* __restrict__ W,
                                                   const float* __restrict__ bias,
                                                   const float* __restrict__ norm_dst,
                                                   float* __restrict__ tout, int n4) {
    __shared__ float Ws[K * 64];
    __shared__ float At[4][K * 4];  // per-wave: 4 nodes' aggregated rows, k-major x node
    const int tid = threadIdx.x;
    for (int i = tid; i < K * 16; i += 256) ((float4*)Ws)[i] = ((const float4*)W)[i];
    __syncthreads();  // only barrier in the kernel

    const int lane = tid & 63, wv = tid >> 6;
    const int gw = (blockIdx.x * 256 + tid) >> 6;
    const int nw = (gridDim.x * 256) >> 6;
    const float blane = bias[lane];
    float* at = &At[wv][0];

    for (int g = gw; g < n4; g += nw) {
        const int node0 = g * 4;
#pragma unroll
        for (int j = 0; j < 4; ++j) {
            const int node = node0 + j;
            const int beg = row_ptr[node], end = row_ptr[node + 1];
            if (K == 64) {
                float a0 = 0.f, a1 = 0.f, a2 = 0.f, a3 = 0.f;
                int i = beg;
                for (; i + 7 < end; i += 8) {
                    float4 c0 = cedge[i + 0], c1 = cedge[i + 1], c2 = cedge[i + 2], c3 = cedge[i + 3];
                    float4 c4 = cedge[i + 4], c5 = cedge[i + 5], c6 = cedge[i + 6], c7 = cedge[i + 7];
                    float h0 = tin[__float_as_int(c0.x) * 64 + lane];
                    float h1 = tin[__float_as_int(c1.x) * 64 + lane];
                    float h2 = tin[__float_as_int(c2.x) * 64 + lane];
                    float h3 = tin[__float_as_int(c3.x) * 64 + lane];
                    float h4 = tin[__float_as_int(c4.x) * 64 + lane];
                    float h5 = tin[__float_as_int(c5.x) * 64 + lane];
                    float h6 = tin[__float_as_int(c6.x) * 64 + lane];
                    float h7 = tin[__float_as_int(c7.x) * 64 + lane];
                    a0 = fmaf(h0, (WSEL == 0) ? c0.y : (WSEL == 1) ? c0.z : c0.w, a0);
                    a1 = fmaf(h1, (WSEL == 0) ? c1.y : (WSEL == 1) ? c1.z : c1.w, a1);
                    a2 = fmaf(h2, (WSEL == 0) ? c2.y : (WSEL == 1) ? c2.z : c2.w, a2);
                    a3 = fmaf(h3, (WSEL == 0) ? c3.y : (WSEL == 1) ? c3.z : c3.w, a3);
                    a0 = fmaf(h4, (WSEL == 0) ? c4.y : (WSEL == 1) ? c4.z : c4.w, a0);
                    a1 = fmaf(h5, (WSEL == 0) ? c5.y : (WSEL == 1) ? c5.z : c5.w, a1);
                    a2 = fmaf(h6, (WSEL == 0) ? c6.y : (WSEL == 1) ? c6.z : c6.w, a2);
                    a3 = fmaf(h7, (WSEL == 0) ? c7.y : (WSEL == 1) ? c7.z : c7.w, a3);
                }
                for (; i < end; ++i) {
                    float4 c0 = cedge[i];
                    float h0 = tin[__float_as_int(c0.x) * 64 + lane];
                    a0 = fmaf(h0, (WSEL == 0) ? c0.y : (WSEL == 1) ? c0.z : c0.w, a0);
                }
                at[lane * 4 + j] = (a0 + a1) + (a2 + a3);
            } else {  // K == 128: two features per lane
                float l0a = 0.f, l1a = 0.f, h0a = 0.f, h1a = 0.f;
                int i = beg;
                for (; i + 3 < end; i += 4) {
                    float4 c0 = cedge[i + 0], c1 = cedge[i + 1], c2 = cedge[i + 2], c3 = cedge[i + 3];
                    int s0 = __float_as_int(c0.x), s1 = __float_as_int(c1.x);
                    int s2 = __float_as_int(c2.x), s3 = __float_as_int(c3.x);
                    float lo0 = tin[s0 * 128 + lane], hi0 = tin[s0 * 128 + 64 + lane];
                    float lo1 = tin[s1 * 128 + lane], hi1 = tin[s1 * 128 + 64 + lane];
                    float lo2 = tin[s2 * 128 + lane], hi2 = tin[s2 * 128 + 64 + lane];
                    float lo3 = tin[s3 * 128 + lane], hi3 = tin[s3 * 128 + 64 + lane];
                    float w0 = (WSEL == 0) ? c0.y : (WSEL == 1) ? c0.z : c0.w;
                    float w1 = (WSEL == 0) ? c1.y : (WSEL == 1) ? c1.z : c1.w;
                    float w2 = (WSEL == 0) ? c2.y : (WSEL == 1) ? c2.z : c2.w;
                    float w3 = (WSEL == 0) ? c3.y : (WSEL == 1) ? c3.z : c3.w;
                    l0a = fmaf(lo0, w0, l0a); h0a = fmaf(hi0, w0, h0a);
                    l1a = fmaf(lo1, w1, l1a); h1a = fmaf(hi1, w1, h1a);
                    l0a = fmaf(lo2, w2, l0a); h0a = fmaf(hi2, w2, h0a);
                    l1a = fmaf(lo3, w3, l1a); h1a = fmaf(hi3, w3, h1a);
                }
                for (; i < end; ++i) {
                    float4 c0 = cedge[i];
                    int s0 = __float_as_int(c0.x);
                    float w0 = (WSEL == 0) ? c0.y : (WSEL == 1) ? c0.z : c0.w;
                    l0a = fmaf(tin[s0 * 128 + lane], w0, l0a);
                    h0a = fmaf(tin[s0 * 128 + 64 + lane], w0, h0a);
                }
                at[lane * 4 + j] = l0a + l1a;
                at[(64 + lane) * 4 + j] = h0a + h1a;
            }
        }
        // same-wave LDS write->read: drain lgkm before the GEMV reads
        asm volatile("s_waitcnt lgkmcnt(0)" ::: "memory");

        // 4-node GEMV: acc_j[lane] = sum_k At[k][j] * Ws[k][lane]
        float acc0 = 0.f, acc1 = 0.f, acc2 = 0.f, acc3 = 0.f;
#pragma unroll 8
        for (int k = 0; k < K; ++k) {
            float4 av = *(const float4*)&at[k * 4];  // broadcast, 16B
            float wval = Ws[k * 64 + lane];          // conflict-free
            acc0 = fmaf(av.x, wval, acc0);
            acc1 = fmaf(av.y, wval, acc1);
            acc2 = fmaf(av.z, wval, acc2);
            acc3 = fmaf(av.w, wval, acc3);
        }
#pragma unroll
        for (int j = 0; j < 4; ++j) {
            float acc = (j == 0) ? acc0 : (j == 1) ? acc1 : (j == 2) ? acc2 : acc3;
            float nd = norm_dst[node0 + j];
            float t = fmaf(acc, nd, blane);
            if (!FINAL) t = fmaxf(t, 0.f);
            tout[(node0 + j) * 64 + lane] = t;
        }
        asm volatile("s_waitcnt lgkmcnt(0)" ::: "memory");  // reads done before next writes
    }
}

#define ZST 76  // Zs row stride

// 64 pairs per block (grid = 3125): Z staged in LDS, P0/P1 from global (L1-broadcast).
__global__ __launch_bounds__(256) void mlp_tile(const float* __restrict__ hfin,
                                                const float* __restrict__ P0,
                                                const float* __restrict__ pb0,
                                                const float* __restrict__ P1,
                                                const float* __restrict__ pb1,
                                                const float* __restrict__ P2,
                                                const float* __restrict__ pb2,
                                                const int* __restrict__ pos_src,
                                                const int* __restrict__ pos_dst,
                                                const int* __restrict__ neg_src,
                                                const int* __restrict__ neg_dst,
                                                float* __restrict__ out, int P) {
    __shared__ float Zs[64][ZST];
    __shared__ float pb0s[64], pb1s[64], P2s[64];
    __shared__ int pas[64], pbs[64];
    const int tid = threadIdx.x;
    const int base = blockIdx.x << 6;
    if (tid < 64) {
        pb0s[tid] = pb0[tid];
        pb1s[tid] = pb1[tid];
        P2s[tid] = P2[tid];
        int p = base + tid;
        pas[tid] = (p < P) ? pos_src[p] : neg_src[p - P];
        pbs[tid] = (p < P) ? pos_dst[p] : neg_dst[p - P];
    }
    const float pb2v = pb2[0];
    const int lane = tid & 63, w = tid >> 6;
    const int tr = tid >> 4, tc = tid & 15;
    __syncthreads();

    // gather + product: wave w owns pairs [w*16, w*16+16); 2 rounds x 16 loads in flight
    {
        const int pbase = w * 16;
#pragma unroll
        for (int r = 0; r < 2; ++r) {
            const int p0 = pbase + r * 8;
            int a0 = pas[p0 + 0], b0 = pbs[p0 + 0];
            int a1 = pas[p0 + 1], b1 = pbs[p0 + 1];
            int a2 = pas[p0 + 2], b2 = pbs[p0 + 2];
            int a3 = pas[p0 + 3], b3 = pbs[p0 + 3];
            int a4 = pas[p0 + 4], b4 = pbs[p0 + 4];
            int a5 = pas[p0 + 5], b5 = pbs[p0 + 5];
            int a6 = pas[p0 + 6], b6 = pbs[p0 + 6];
            int a7 = pas[p0 + 7], b7 = pbs[p0 + 7];
            float ha0 = hfin[a0 * 64 + lane], hb0 = hfin[b0 * 64 + lane];
            float ha1 = hfin[a1 * 64 + lane], hb1 = hfin[b1 * 64 + lane];
            float ha2 = hfin[a2 * 64 + lane], hb2 = hfin[b2 * 64 + lane];
            float ha3 = hfin[a3 * 64 + lane], hb3 = hfin[b3 * 64 + lane];
            float ha4 = hfin[a4 * 64 + lane], hb4 = hfin[b4 * 64 + lane];
            float ha5 = hfin[a5 * 64 + lane], hb5 = hfin[b5 * 64 + lane];
            float ha6 = hfin[a6 * 64 + lane], hb6 = hfin[b6 * 64 + lane];
            float ha7 = hfin[a7 * 64 + lane], hb7 = hfin[b7 * 64 + lane];
            Zs[p0 + 0][lane] = ha0 * hb0;
            Zs[p0 + 1][lane] = ha1 * hb1;
            Zs[p0 + 2][lane] = ha2 * hb2;
            Zs[p0 + 3][lane] = ha3 * hb3;
            Zs[p0 + 4][lane] = ha4 * hb4;
            Zs[p0 + 5][lane] = ha5 * hb5;
            Zs[p0 + 6][lane] = ha6 * hb6;
            Zs[p0 + 7][lane] = ha7 * hb7;
        }
    }
    __syncthreads();

    // layer 0: Z1 = relu(Z @ P0 + pb0)
    float4 acc0, acc1, acc2, acc3;
    {
        float4 binit = *(const float4*)&pb0s[tc * 4];
        acc0 = binit; acc1 = binit; acc2 = binit; acc3 = binit;
    }
#pragma unroll 4
    for (int k4 = 0; k4 < 16; ++k4) {
        const int kb = k4 * 4;
        float4 xv0 = *(const float4*)&Zs[tr * 4 + 0][kb];
        float4 xv1 = *(const float4*)&Zs[tr * 4 + 1][kb];
        float4 xv2 = *(const float4*)&Zs[tr * 4 + 2][kb];
        float4 xv3 = *(const float4*)&Zs[tr * 4 + 3][kb];
        const float* wb = &P0[kb * 64 + tc * 4];
        float4 wk;
        wk = *(const float4*)(wb);
        row_fma(acc0, xv0.x, wk); row_fma(acc1, xv1.x, wk); row_fma(acc2, xv2.x, wk); row_fma(acc3, xv3.x, wk);
        wk = *(const float4*)(wb + 64);
        row_fma(acc0, xv0.y, wk); row_fma(acc1, xv1.y, wk); row_fma(acc2, xv2.y, wk); row_fma(acc3, xv3.y, wk);
        wk = *(const float4*)(wb + 128);
        row_fma(acc0, xv0.z, wk); row_fma(acc1, xv1.z, wk); row_fma(acc2, xv2.z, wk); row_fma(acc3, xv3.z, wk);
        wk = *(const float4*)(wb + 192);
        row_fma(acc0, xv0.w, wk); row_fma(acc1, xv1.w, wk); row_fma(acc2, xv2.w, wk); row_fma(acc3, xv3.w, wk);
    }
    __syncthreads();
#pragma unroll
    for (int i = 0; i < 4; ++i) {
        float4 o = (i == 0) ? acc0 : (i == 1) ? acc1 : (i == 2) ? acc2 : acc3;
        o.x = fmaxf(o.x, 0.f); o.y = fmaxf(o.y, 0.f); o.z = fmaxf(o.z, 0.f); o.w = fmaxf(o.w, 0.f);
        *(float4*)&Zs[tr * 4 + i][tc * 4] = o;
    }
    __syncthreads();

    // layer 1: Z2 = relu(Z1 @ P1 + pb1)
    {
        float4 binit = *(const float4*)&pb1s[tc * 4];
        acc0 = binit; acc1 = binit; acc2 = binit; acc3 = binit;
    }
#pragma unroll 4
    for (int k4 = 0; k4 < 16; ++k4) {
        const int kb = k4 * 4;
        float4 xv0 = *(const float4*)&Zs[tr * 4 + 0][kb];
        float4 xv1 = *(const float4*)&Zs[tr * 4 + 1][kb];
        float4 xv2 = *(const float4*)&Zs[tr * 4 + 2][kb];
        float4 xv3 = *(const float4*)&Zs[tr * 4 + 3][kb];
        const float* wb = &P1[kb * 64 + tc * 4];
        float4 wk;
        wk = *(const float4*)(wb);
        row_fma(acc0, xv0.x, wk); row_fma(acc1, xv1.x, wk); row_fma(acc2, xv2.x, wk); row_fma(acc3, xv3.x, wk);
        wk = *(const float4*)(wb + 64);
        row_fma(acc0, xv0.y, wk); row_fma(acc1, xv1.y, wk); row_fma(acc2, xv2.y, wk); row_fma(acc3, xv3.y, wk);
        wk = *(const float4*)(wb + 128);
        row_fma(acc0, xv0.z, wk); row_fma(acc1, xv1.z, wk); row_fma(acc2, xv2.z, wk); row_fma(acc3, xv3.z, wk);
        wk = *(const float4*)(wb + 192);
        row_fma(acc0, xv0.w, wk); row_fma(acc1, xv1.w, wk); row_fma(acc2, xv2.w, wk); row_fma(acc3, xv3.w, wk);
    }
    __syncthreads();
#pragma unroll
    for (int i = 0; i < 4; ++i) {
        float4 o = (i == 0) ? acc0 : (i == 1) ? acc1 : (i == 2) ? acc2 : acc3;
        o.x = fmaxf(o.x, 0.f); o.y = fmaxf(o.y, 0.f); o.z = fmaxf(o.z, 0.f); o.w = fmaxf(o.w, 0.f);
        *(float4*)&Zs[tr * 4 + i][tc * 4] = o;
    }
    __syncthreads();

    // final GEMV: out[p] = Z2[p] . P2 + pb2
    {
        int p = tid >> 2, kq = tid & 3;
        float s = 0.f;
#pragma unroll
        for (int i = 0; i < 16; ++i) s = fmaf(Zs[p][kq * 16 + i], P2s[kq * 16 + i], s);
        s += __shfl_xor(s, 1, 64);
        s += __shfl_xor(s, 2, 64);
        if (kq == 0) out[base + p] = s + pb2v;
    }
}

extern "C" void kernel_launch(void* const* d_in, const int* in_sizes, int n_in,
                              void* d_out, int out_size, void* d_ws, size_t ws_size,
                              hipStream_t stream) {
    const float* x     = (const float*)d_in[0];
    const float* ew    = (const float*)d_in[1];  // (3, E)
    const int* src     = (const int*)d_in[2];
    const int* dst     = (const int*)d_in[3];
    const int* pos_src = (const int*)d_in[4];
    const int* pos_dst = (const int*)d_in[5];
    const int* neg_src = (const int*)d_in[6];
    const int* neg_dst = (const int*)d_in[7];
    const float* W0    = (const float*)d_in[8];
    const float* b0    = (const float*)d_in[9];
    const float* W1    = (const float*)d_in[10];
    const float* b1    = (const float*)d_in[11];
    const float* W2    = (const float*)d_in[12];
    const float* b2    = (const float*)d_in[13];
    const float* P0    = (const float*)d_in[14];
    const float* pb0   = (const float*)d_in[15];
    const float* P1    = (const float*)d_in[16];
    const float* pb1   = (const float*)d_in[17];
    const float* P2    = (const float*)d_in[18];
    const float* pb2   = (const float*)d_in[19];
    float* out = (float*)d_out;

    float* ws = (float*)d_ws;
    float* norm_src = ws;                     // N
    float* norm_dst = ws + 100000;            // N
    int* cursor     = (int*)(ws + 200000);    // N
    int* deg_in     = (int*)(ws + 300000);    // N
    int* row_ptr    = (int*)(ws + 400000);    // N+1
    float4* cedge   = (float4*)(ws + 500004); // E
    float* tA       = ws + 4500004;           // N*64
    float* tB       = ws + 10900004;          // N*64

    // pre-layer0 scratch inside tA region (not yet live)
    int* repl      = (int*)tA;            // 16*NN ints: [deg_out x8][deg_in x8]
    int* tmp_excl  = (int*)tA + 16 * NN;  // NN
    int* blocksums = (int*)tA + 17 * NN;  // SCAN_NB

    hipMemsetAsync(repl, 0, 16 * NN * sizeof(int), stream);
    deg_kernel<<<(NE / 4 + 255) / 256, 256, 0, stream>>>((const int4*)src, (const int4*)dst,
                                                         repl, NE / 4);
    reduce_norm_kernel<<<(NN + 255) / 256, 256, 0, stream>>>(repl, norm_src, norm_dst, deg_in, NN);
    scan_block<<<SCAN_NB, 1024, 0, stream>>>(deg_in, tmp_excl, blocksums, NN);
    scan_sums<<<1, 128, 0, stream>>>(blocksums, SCAN_NB);
    scan_apply<<<SCAN_NB, 1024, 0, stream>>>(tmp_excl, blocksums, row_ptr, cursor, NN);
    csr_fill<<<2048, 256, 0, stream>>>(src, dst, ew, norm_src, cursor, cedge, NE);

    const int NG = NN / 4;  // 25000 node groups

    // layer 0: tA = relu((sum cw0*x[src]) @ W0 * nd + b0)
    fused_layer<128, 0, false><<<4096, 256, 0, stream>>>(x, cedge, row_ptr, W0, b0, norm_dst, tA, NG);
    // layer 1: tB = relu((sum cw1*tA[src]) @ W1 * nd + b1)
    fused_layer<64, 1, false><<<4096, 256, 0, stream>>>(tA, cedge, row_ptr, W1, b1, norm_dst, tB, NG);
    // layer 2 (final, no relu): tA = (sum cw2*tB[src]) @ W2 * nd + b2
    fused_layer<64, 2, true><<<4096, 256, 0, stream>>>(tB, cedge, row_ptr, W2, b2, norm_dst, tA, NG);

    // MLP over pos & neg pairs
    mlp_tile<<<(2 * NP) / 64, 256, 0, stream>>>(tA, P0, pb0, P1, pb1, P2, pb2,
                                                pos_src, pos_dst, neg_src, neg_dst, out, NP);
}